// Round 1
// baseline (112.568 us; speedup 1.0000x reference)
//
#include <hip/hip_runtime.h>
#include <hip/hip_bf16.h>

// out[b,n] = -(||x_b||^2 - 2 x.y + ||y_n||^2) = 2*x.y - ||x_b||^2 - ||y_n||^2
// x: [M=4096, K=1024] f32   y: [N=8192, K=1024] f32   out: [M, N] f32
//
// Strategy: prep kernel converts x,y -> bf16 in d_ws + computes f32 row norms;
// main kernel is an m97-structure bf16 MFMA GEMM (128x128 tile, BK=64,
// global_load_lds 16B staging, 16x16x32 bf16 MFMA) with fused epilogue.

typedef __attribute__((ext_vector_type(8))) short bf16x8;
typedef __attribute__((ext_vector_type(4))) float f32x4;

#define BM 128
#define BN 128
#define BK 64
#define KDIM 1024

__device__ __forceinline__ short f2bf(float f) {
    __hip_bfloat16 h = __float2bfloat16(f);
    return *reinterpret_cast<short*>(&h);
}

__device__ __forceinline__ void gld16(const void* g, void* l) {
    __builtin_amdgcn_global_load_lds(
        (const __attribute__((address_space(1))) unsigned int*)g,
        (__attribute__((address_space(3))) unsigned int*)l,
        16, 0, 0);
}

// ---------------- prep: f32 -> bf16 + row squared-norms -------------------
__global__ __launch_bounds__(256) void prep_kernel(
    const float* __restrict__ x, const float* __restrict__ y,
    short* __restrict__ xb, short* __restrict__ yb,
    float* __restrict__ xsq, float* __restrict__ ysq, int M, int N)
{
    int row = blockIdx.x;
    const float* src;
    short* dst;
    float* nrm;
    if (row < M) {
        src = x + (size_t)row * KDIM;
        dst = xb + (size_t)row * KDIM;
        nrm = xsq + row;
    } else {
        int r = row - M;
        src = y + (size_t)r * KDIM;
        dst = yb + (size_t)r * KDIM;
        nrm = ysq + r;
    }
    int t = threadIdx.x;                       // 256 threads, 4 floats each
    float4 v = ((const float4*)src)[t];
    float s = v.x * v.x + v.y * v.y + v.z * v.z + v.w * v.w;
    short4 o;
    o.x = f2bf(v.x); o.y = f2bf(v.y); o.z = f2bf(v.z); o.w = f2bf(v.w);
    ((short4*)dst)[t] = o;

    // block reduction of s
    #pragma unroll
    for (int off = 32; off > 0; off >>= 1) s += __shfl_down(s, off, 64);
    __shared__ float red[4];
    if ((t & 63) == 0) red[t >> 6] = s;
    __syncthreads();
    if (t == 0) *nrm = red[0] + red[1] + red[2] + red[3];
}

// ---------------- main bf16 MFMA GEMM with fused epilogue -----------------
__global__ __launch_bounds__(256, 2) void gemm_l2(
    const short* __restrict__ xb, const short* __restrict__ yb,
    const float* __restrict__ xsq, const float* __restrict__ ysq,
    float* __restrict__ out, int M, int N)
{
    __shared__ __align__(16) short As[BM * BK];   // 16 KB
    __shared__ __align__(16) short Bs[BN * BK];   // 16 KB

    const int nwg = gridDim.x;
    const int ntn = N / BN;
    // bijective XCD swizzle (nwg % 8 == 0 here: 32*64 = 2048)
    int bid = blockIdx.x;
    int cpx = nwg >> 3;
    int swz = (bid & 7) * cpx + (bid >> 3);
    int tm = swz / ntn;
    int tn = swz % ntn;

    const int tid  = threadIdx.x;
    const int wid  = tid >> 6;          // wave 0..3  (2x2)
    const int lane = tid & 63;
    const int wm = wid >> 1;            // 0..1
    const int wn = wid & 1;             // 0..1

    // staging descriptors: wave `wid` fills chunks wid*4 .. wid*4+3 of each tile
    const short* agp[4];
    const short* bgp[4];
    short* alp[4];
    short* blp[4];
    #pragma unroll
    for (int c = 0; c < 4; ++c) {
        int gc  = wid * 4 + c;                  // 0..15
        int row = gc * 8 + (lane >> 3);         // 0..127
        int col = (lane & 7) * 8;               // 0..56, 16B granules
        agp[c] = xb + (size_t)(tm * BM + row) * KDIM + col;
        bgp[c] = yb + (size_t)(tn * BN + row) * KDIM + col;
        alp[c] = As + gc * 512 + lane * 8;      // contiguous: base + lane*16B
        blp[c] = Bs + gc * 512 + lane * 8;
    }

    f32x4 acc[4][4] = {};

    const int lm = lane & 15;        // fragment row/col within 16
    const int lk = (lane >> 4) * 8;  // fragment k offset

    for (int kt = 0; kt < KDIM / BK; ++kt) {
        const int ko = kt * BK;
        #pragma unroll
        for (int c = 0; c < 4; ++c) {
            gld16(agp[c] + ko, alp[c]);
            gld16(bgp[c] + ko, blp[c]);
        }
        __syncthreads();   // waits vmcnt(0) -> tiles resident

        #pragma unroll
        for (int ks = 0; ks < BK / 32; ++ks) {
            bf16x8 af[4], bfr[4];
            #pragma unroll
            for (int i = 0; i < 4; ++i) {
                af[i]  = *(const bf16x8*)&As[(wm * 64 + i * 16 + lm) * BK + ks * 32 + lk];
                bfr[i] = *(const bf16x8*)&Bs[(wn * 64 + i * 16 + lm) * BK + ks * 32 + lk];
            }
            #pragma unroll
            for (int i = 0; i < 4; ++i)
                #pragma unroll
                for (int j = 0; j < 4; ++j)
                    acc[i][j] = __builtin_amdgcn_mfma_f32_16x16x32_bf16(
                        af[i], bfr[j], acc[i][j], 0, 0, 0);
        }
        __syncthreads();
    }

    // epilogue: out = 2*acc - xsq[row] - ysq[col]
    // C/D layout (16x16): col = lane&15, row = (lane>>4)*4 + reg
    #pragma unroll
    for (int i = 0; i < 4; ++i) {
        int r0 = tm * BM + wm * 64 + i * 16 + (lane >> 4) * 4;
        #pragma unroll
        for (int j = 0; j < 4; ++j) {
            int c = tn * BN + wn * 64 + j * 16 + (lane & 15);
            float ysv = ysq[c];
            #pragma unroll
            for (int r = 0; r < 4; ++r) {
                out[(size_t)(r0 + r) * N + c] =
                    2.0f * acc[i][j][r] - xsq[r0 + r] - ysv;
            }
        }
    }
}

// ---------------- fallback (only if ws too small): exact f32 --------------
__global__ __launch_bounds__(256) void fallback_l2(
    const float* __restrict__ x, const float* __restrict__ y,
    float* __restrict__ out, int M, int N)
{
    int tx = threadIdx.x & 15, ty = threadIdx.x >> 4;
    int row = blockIdx.y * 16 + ty;
    int col = blockIdx.x * 16 + tx;
    __shared__ float xs[16][17], ys[16][17];
    float s = 0.f;
    for (int k0 = 0; k0 < KDIM; k0 += 16) {
        xs[ty][tx] = x[(size_t)row * KDIM + k0 + tx];
        ys[ty][tx] = y[(size_t)(blockIdx.x * 16 + ty) * KDIM + k0 + tx];
        __syncthreads();
        #pragma unroll
        for (int kk = 0; kk < 16; ++kk) {
            float d = xs[ty][kk] - ys[tx][kk];
            s += d * d;
        }
        __syncthreads();
    }
    out[(size_t)row * N + col] = -s;
}

extern "C" void kernel_launch(void* const* d_in, const int* in_sizes, int n_in,
                              void* d_out, int out_size, void* d_ws, size_t ws_size,
                              hipStream_t stream) {
    const float* x = (const float*)d_in[0];
    const float* y = (const float*)d_in[1];
    float* out = (float*)d_out;
    const int M = in_sizes[0] / KDIM;   // 4096
    const int N = in_sizes[1] / KDIM;   // 8192

    size_t need = (size_t)(M + N) * KDIM * sizeof(short)
                + (size_t)(M + N) * sizeof(float) + 256;
    if (ws_size >= need) {
        char* w = (char*)d_ws;
        short* xb  = (short*)w;
        short* yb  = xb + (size_t)M * KDIM;
        float* xsq = (float*)(yb + (size_t)N * KDIM);
        float* ysq = xsq + M;

        prep_kernel<<<M + N, 256, 0, stream>>>(x, y, xb, yb, xsq, ysq, M, N);
        int grid = (M / BM) * (N / BN);   // 32*64 = 2048
        gemm_l2<<<grid, 256, 0, stream>>>(xb, yb, xsq, ysq, out, M, N);
    } else {
        dim3 g(N / 16, M / 16);
        fallback_l2<<<g, 256, 0, stream>>>(x, y, out, M, N);
    }
}

// Round 2
// 100.802 us; speedup vs baseline: 1.1167x; 1.1167x over previous
//
#include <hip/hip_runtime.h>
#include <hip/hip_bf16.h>

// out[b,n] = 2*x.y - ||x_b||^2 - ||y_n||^2
// x: [M=4096, K=1024] f32   y: [N=8192, K=1024] f32   out: [M, N] f32
//
// Round 2: 256x256 8-phase-style bf16 MFMA GEMM (T1 XCD swizzle + T2 LDS
// XOR swizzle via pre-swizzled global src + T3/T4 phased counted-vmcnt
// pipeline + T5 setprio). Prep kernel converts to bf16 + row norms.

typedef __attribute__((ext_vector_type(8))) short bf16x8;
typedef __attribute__((ext_vector_type(4))) float f32x4;

#define BM 256
#define BN 256
#define BK 64
#define KDIM 1024
#define NT (KDIM / BK)   // 16 K-tiles

__device__ __forceinline__ short f2bf(float f) {
    __hip_bfloat16 h = __float2bfloat16(f);
    return *reinterpret_cast<short*>(&h);
}

__device__ __forceinline__ void gld16(const short* g, const short* l) {
    __builtin_amdgcn_global_load_lds(
        (const __attribute__((address_space(1))) unsigned int*)g,
        (__attribute__((address_space(3))) unsigned int*)l,
        16, 0, 0);
}

// ---------------- prep: f32 -> bf16 + row squared-norms -------------------
__global__ __launch_bounds__(256) void prep_kernel(
    const float* __restrict__ x, const float* __restrict__ y,
    short* __restrict__ xb, short* __restrict__ yb,
    float* __restrict__ xsq, float* __restrict__ ysq, int M, int N)
{
    int row = blockIdx.x;
    const float* src;
    short* dst;
    float* nrm;
    if (row < M) {
        src = x + (size_t)row * KDIM;
        dst = xb + (size_t)row * KDIM;
        nrm = xsq + row;
    } else {
        int r = row - M;
        src = y + (size_t)r * KDIM;
        dst = yb + (size_t)r * KDIM;
        nrm = ysq + r;
    }
    int t = threadIdx.x;                       // 256 threads, 4 floats each
    float4 v = ((const float4*)src)[t];
    float s = v.x * v.x + v.y * v.y + v.z * v.z + v.w * v.w;
    short4 o;
    o.x = f2bf(v.x); o.y = f2bf(v.y); o.z = f2bf(v.z); o.w = f2bf(v.w);
    ((short4*)dst)[t] = o;

    #pragma unroll
    for (int off = 32; off > 0; off >>= 1) s += __shfl_down(s, off, 64);
    __shared__ float red[4];
    if ((t & 63) == 0) red[t >> 6] = s;
    __syncthreads();
    if (t == 0) *nrm = red[0] + red[1] + red[2] + red[3];
}

// ---------------- main 256x256 phased bf16 MFMA GEMM ----------------------
__global__ __launch_bounds__(512, 2) void gemm_l2(
    const short* __restrict__ xb, const short* __restrict__ yb,
    const float* __restrict__ xsq, const float* __restrict__ ysq,
    float* __restrict__ out, int M, int N)
{
    // 2 x (256x64) bf16 tiles for A and B, double buffered: 128 KiB
    __shared__ __align__(16) short As[2][BM * BK];
    __shared__ __align__(16) short Bs[2][BN * BK];

    const int nwg = gridDim.x;          // 512 (divisible by 8)
    const int ntn = N / BN;             // 32
    const int bid = blockIdx.x;
    const int cpx = nwg >> 3;
    const int swz = (bid & 7) * cpx + (bid >> 3);   // bijective XCD swizzle
    const int tm = swz / ntn;
    const int tn = swz % ntn;

    const int tid  = threadIdx.x;       // 512 threads = 8 waves
    const int wid  = tid >> 6;
    const int lane = tid & 63;
    const int wm   = wid >> 2;          // 0..1  (wave tile: 128 x 64)
    const int wn   = wid & 3;           // 0..3
    const int l15  = lane & 15;
    const int hi   = lane >> 4;         // 0..3
    const int s8   = lane & 7;          // == frag row & 7 (swizzle key)

    // ---- staging descriptors: 4 chunks of 64 rows each, per matrix ----
    // physical LDS layout is LINEAR (gld_lds writes base + lane*16B);
    // the XOR swizzle is applied by permuting the GLOBAL source block.
    const int srow = wid * 8 + (lane >> 3);          // row within chunk
    const int scb  = lane & 7;                       // physical 16B block
    const int cbs  = scb ^ ((lane >> 3) & 7);        // swizzled source block
    const short* aG[4];
    const short* bG[4];
    int lofs[4];
    #pragma unroll
    for (int l = 0; l < 4; ++l) {
        int row = l * 64 + srow;
        aG[l] = xb + (size_t)(tm * BM + row) * KDIM + cbs * 8;
        bG[l] = yb + (size_t)(tn * BN + row) * KDIM + cbs * 8;
        lofs[l] = row * BK + scb * 8;                // == chunk base + lane*8
    }

    // ---- fragment LDS base offsets (shorts), swizzle applied on read ----
    int abase[8], bbase[4];
    #pragma unroll
    for (int m = 0; m < 8; ++m) abase[m] = (wm * 128 + m * 16 + l15) * BK;
    #pragma unroll
    for (int n = 0; n < 4; ++n) bbase[n] = (wn * 64 + n * 16 + l15) * BK;

    f32x4 acc[8][4] = {};

    // ---- prologue: stage tile 0 into buffer 0 (8 loads/wave) ----
    #pragma unroll
    for (int c = 0; c < 4; ++c) {
        gld16(aG[c], &As[0][lofs[c]]);
        gld16(bG[c], &Bs[0][lofs[c]]);
    }

    for (int t = 0; t < NT; ++t) {
        const int cur = t & 1;
        const bool pre = (t + 1 < NT);
        const size_t ko = (size_t)(t + 1) * BK;

        // tile top: issue chunk 0 of next tile, then wait for THIS tile's
        // 8 loads (counted vmcnt: next tile's 2 stay in flight), barrier.
        if (pre) {
            gld16(aG[0] + ko, &As[cur ^ 1][lofs[0]]);
            gld16(bG[0] + ko, &Bs[cur ^ 1][lofs[0]]);
            asm volatile("s_waitcnt vmcnt(2)" ::: "memory");
        } else {
            asm volatile("s_waitcnt vmcnt(0)" ::: "memory");
        }
        asm volatile("s_barrier" ::: "memory");

        #pragma unroll
        for (int p = 0; p < 4; ++p) {
            const int ks = p >> 1;      // k-step (0,1)
            const int mh = p & 1;       // m-half (0,1)
            const int bo = (((ks << 2) | hi) ^ s8) << 3;   // swizzled block

            bf16x8 a[4], b[4];
            #pragma unroll
            for (int i = 0; i < 4; ++i)
                a[i] = *(const bf16x8*)&As[cur][abase[mh * 4 + i] + bo];
            #pragma unroll
            for (int n = 0; n < 4; ++n)
                b[n] = *(const bf16x8*)&Bs[cur][bbase[n] + bo];

            if (p > 0 && pre) {         // spread remaining prefetch loads
                gld16(aG[p] + ko, &As[cur ^ 1][lofs[p]]);
                gld16(bG[p] + ko, &Bs[cur ^ 1][lofs[p]]);
            }

            asm volatile("s_barrier" ::: "memory");
            __builtin_amdgcn_s_setprio(1);
            #pragma unroll
            for (int i = 0; i < 4; ++i)
                #pragma unroll
                for (int n = 0; n < 4; ++n)
                    acc[mh * 4 + i][n] = __builtin_amdgcn_mfma_f32_16x16x32_bf16(
                        a[i], b[n], acc[mh * 4 + i][n], 0, 0, 0);
            __builtin_amdgcn_s_setprio(0);
            asm volatile("s_barrier" ::: "memory");
        }
    }

    // ---- epilogue: out = 2*acc - xsq[row] - ysq[col] ----
    // C/D layout (16x16): col = lane&15, row = (lane>>4)*4 + reg
    #pragma unroll
    for (int i = 0; i < 8; ++i) {
        int r0 = tm * BM + wm * 128 + i * 16 + hi * 4;
        #pragma unroll
        for (int n = 0; n < 4; ++n) {
            int c = tn * BN + wn * 64 + n * 16 + l15;
            float ysv = ysq[c];
            #pragma unroll
            for (int r = 0; r < 4; ++r) {
                out[(size_t)(r0 + r) * N + c] =
                    2.0f * acc[i][n][r] - xsq[r0 + r] - ysv;
            }
        }
    }
}

// ---------------- fallback (only if ws too small): exact f32 --------------
__global__ __launch_bounds__(256) void fallback_l2(
    const float* __restrict__ x, const float* __restrict__ y,
    float* __restrict__ out, int M, int N)
{
    int tx = threadIdx.x & 15, ty = threadIdx.x >> 4;
    int row = blockIdx.y * 16 + ty;
    int col = blockIdx.x * 16 + tx;
    __shared__ float xs[16][17], ys[16][17];
    float s = 0.f;
    for (int k0 = 0; k0 < KDIM; k0 += 16) {
        xs[ty][tx] = x[(size_t)row * KDIM + k0 + tx];
        ys[ty][tx] = y[(size_t)(blockIdx.x * 16 + ty) * KDIM + k0 + tx];
        __syncthreads();
        #pragma unroll
        for (int kk = 0; kk < 16; ++kk) {
            float d = xs[ty][kk] - ys[tx][kk];
            s += d * d;
        }
        __syncthreads();
    }
    out[(size_t)row * N + col] = -s;
}

extern "C" void kernel_launch(void* const* d_in, const int* in_sizes, int n_in,
                              void* d_out, int out_size, void* d_ws, size_t ws_size,
                              hipStream_t stream) {
    const float* x = (const float*)d_in[0];
    const float* y = (const float*)d_in[1];
    float* out = (float*)d_out;
    const int M = in_sizes[0] / KDIM;   // 4096
    const int N = in_sizes[1] / KDIM;   // 8192

    size_t need = (size_t)(M + N) * KDIM * sizeof(short)
                + (size_t)(M + N) * sizeof(float) + 256;
    if (ws_size >= need) {
        char* w = (char*)d_ws;
        short* xb  = (short*)w;
        short* yb  = xb + (size_t)M * KDIM;
        float* xsq = (float*)(yb + (size_t)N * KDIM);
        float* ysq = xsq + M;

        prep_kernel<<<M + N, 256, 0, stream>>>(x, y, xb, yb, xsq, ysq, M, N);
        int grid = (M / BM) * (N / BN);   // 16*32 = 512 (divisible by 8)
        gemm_l2<<<grid, 512, 0, stream>>>(xb, yb, xsq, ysq, out, M, N);
    } else {
        dim3 g(N / 16, M / 16);
        fallback_l2<<<g, 256, 0, stream>>>(x, y, out, M, N);
    }
}